// Round 9
// baseline (177.079 us; speedup 1.0000x reference)
//
#include <hip/hip_runtime.h>
#include <cstddef>
#include <cstdint>

#define BN_EPS 1e-5f

typedef __attribute__((ext_vector_type(8))) __bf16 bf16x8;
typedef __attribute__((ext_vector_type(4))) float f32x4;

__device__ inline unsigned short f2bf(float f) {
    unsigned u = __builtin_bit_cast(unsigned, f);
    unsigned r = (u + 0x7fff + ((u >> 16) & 1)) >> 16;
    return (unsigned short)r;
}
__device__ inline float bf2f(unsigned short u) {
    return __builtin_bit_cast(float, (unsigned)u << 16);
}

#define GLDS16(g, l)                                                        \
    __builtin_amdgcn_global_load_lds(                                       \
        (const __attribute__((address_space(1))) void*)(g),                 \
        (__attribute__((address_space(3))) void*)(l), 16, 0, 0)

// ===========================================================================
// Prep kernel (round-8 proven, unchanged)
// ===========================================================================
template<int HW, int HWT>
__device__ inline void transpose_body(int rb, const float* __restrict__ in,
                                      unsigned short* __restrict__ out)
{
    __shared__ unsigned short tl[64][66];
    const int tid  = threadIdx.x;
    const int lane = tid & 63, w = tid >> 6;
    const int b  = rb / (HWT * 4);
    const int r2 = rb - b * (HWT * 4);
    const int ht = r2 >> 2, ct = r2 & 3;
    const int c0 = ct * 64, hw0 = ht * 64;
    const int hw = hw0 + lane;
    const float* ib = in + ((size_t)b * 256 + c0) * HW;
    #pragma unroll
    for (int r = 0; r < 16; ++r) {
        const int cl = w * 16 + r;
        const float v = (hw < HW) ? ib[(size_t)cl * HW + hw] : 0.f;
        tl[cl][lane] = f2bf(v);
    }
    __syncthreads();
    unsigned short* ob = out + ((size_t)b * HW + hw0) * 256 + c0 + lane;
    #pragma unroll
    for (int jj = 0; jj < 16; ++jj) {
        const int j = jj * 4 + w;
        if (hw0 + j < HW) ob[(size_t)j * 256] = tl[lane][j];
    }
}

__global__ __launch_bounds__(256)
void prep_kernel(const float* __restrict__ srch, const float* __restrict__ kin,
                 const float* __restrict__ cs_w, const float* __restrict__ ck_w,
                 const float* __restrict__ h1_w, const float* __restrict__ h2_w,
                 unsigned short* __restrict__ s16, unsigned short* __restrict__ k16,
                 unsigned short* __restrict__ wTs, unsigned short* __restrict__ wTk,
                 unsigned short* __restrict__ h1w16, unsigned short* __restrict__ h2w16,
                 int GS, int GK)
{
    const int bid = blockIdx.x;
    if (bid < GS) {
        transpose_body<961, 16>(bid, srch, s16);
    } else if (bid < GS + GK) {
        transpose_body<49, 1>(bid - GS, kin, k16);
    } else {
        const int i = (bid - GS - GK) * 256 + threadIdx.x;
        if (i < 589824) {
            const int ic = i & 255, t = i >> 8, oc = t & 255, khkw = t >> 8;
            wTs[i] = f2bf(cs_w[(size_t)((oc << 8) + ic) * 9 + khkw]);
        } else if (i < 1179648) {
            const int j = i - 589824;
            const int ic = j & 255, t = j >> 8, oc = t & 255, khkw = t >> 8;
            wTk[j] = f2bf(ck_w[(size_t)((oc << 8) + ic) * 9 + khkw]);
        } else if (i < 1245184) {
            const int j = i - 1179648;
            h1w16[j] = f2bf(h1_w[j]);
        } else if (i < 1249280) {
            const int j = i - 1245184;
            const int oc = j >> 8, ic = j & 255;
            h2w16[j] = (oc < 10) ? f2bf(h2_w[oc * 256 + ic]) : (unsigned short)0;
        }
    }
}

// ===========================================================================
// 8-phase 256x256 MFMA implicit-GEMM 3x3 conv + BN + ReLU, both branches.
// BM=256(all oc) x BN=256(pos), BK=64, NT=36 K-tiles (9 taps x 4 ic-slices).
// 8 waves (2m x 4n), per-wave C = 128x64. LDS 2x(A 32K + B 32K) = 128 KB.
// Per tile: 4 phases; phase q computes C-quadrant q (16 MFMA); phase 0 also
// loads all B-frags. Stages: p0->A0(kt+1), p1->A1(kt+1), p2->B0(kt+2),
// p3->B1(kt+2); vmcnt(4) at tile end (vmcnt(0) at NT-2). Hazard inventory:
// every staged region's last reader is >=2 barriers in the past.
// Per-acc K-order identical to rounds 3-8 -> bitwise-identical output.
// ===========================================================================
struct ConvParams {
    const unsigned short* bsrc;   // NHWC bf16 [B*IH*IW][256]
    const unsigned short* wT;     // bf16 [9][256 oc][256 ic]
    const float *bg, *bb, *bm, *bv;
    unsigned short* out;          // NHWC bf16 [pos][256]
    int IH, IW, OW, PPB, N;
};

#define STAGE_A(tkt, h)                                                       \
    { const int _b = (tkt) & 1;                                               \
      const size_t _w = ((size_t)((tkt) >> 2) << 16) + (((tkt) & 3) << 6);    \
      GLDS16(P.wT + _w + aoff[(h)*2],     &Alds[_b][ldsb[(h)*2]]);            \
      GLDS16(P.wT + _w + aoff[(h)*2 + 1], &Alds[_b][ldsb[(h)*2 + 1]]); }

#define STAGE_B(tkt, h)                                                       \
    { const int _b = (tkt) & 1;                                               \
      const int _kk = (tkt) >> 2;                                             \
      const int _kh = _kk / 3, _kw = _kk - 3 * _kh;                           \
      const int _tap = _kh * P.IW + _kw;                                      \
      const int _ic = ((tkt) & 3) << 6;                                       \
      GLDS16(P.bsrc + (size_t)(brows[(h)*2] + _tap) * 256 + _ic + gs8,        \
             &Blds[_b][ldsb[(h)*2]]);                                         \
      GLDS16(P.bsrc + (size_t)(brows[(h)*2+1] + _tap) * 256 + _ic + gs8,      \
             &Blds[_b][ldsb[(h)*2+1]]); }

__global__ __launch_bounds__(512, 2)
void conv3x3_8ph_kernel(ConvParams S, ConvParams K, int Gs)
{
    constexpr int NT = 36;
    __shared__ __align__(16) unsigned short Alds[2][256 * 64];
    __shared__ __align__(16) unsigned short Blds[2][256 * 64];

    const int tid  = threadIdx.x;
    const int lane = tid & 63;
    const int wid  = tid >> 6;

    const int raw = blockIdx.x;
    ConvParams P;
    int tileid;
    if (raw < Gs) {
        P = S;
        const int q8 = Gs >> 3, r8 = Gs & 7;
        const int xcd = raw & 7, seq = raw >> 3;
        tileid = (xcd < r8 ? xcd * (q8 + 1) : r8 * (q8 + 1) + (xcd - r8) * q8) + seq;
    } else {
        P = K;
        tileid = raw - Gs;
    }
    const int p0 = tileid << 8;

    // ---- staging maps: 4 slots s=(h<<1)|j, rowb = h*128 + j*64 + wid*8 ----
    const int gs  = (lane & 7) ^ (lane >> 3);
    const int gs8 = gs * 8;
    int aoff[4], brows[4], ldsb[4];
    #pragma unroll
    for (int s = 0; s < 4; ++s) {
        const int rowb = (s >> 1) * 128 + (s & 1) * 64 + wid * 8;
        const int row  = rowb + (lane >> 3);
        aoff[s] = row * 256 + gs8;
        int pg = p0 + row; if (pg > P.N - 1) pg = P.N - 1;
        const int bb_ = pg / P.PPB;
        const int p   = pg - bb_ * P.PPB;
        const int oh  = p / P.OW, ow = p - oh * P.OW;
        brows[s] = (bb_ * P.IH + oh) * P.IW + ow;
        ldsb[s]  = rowb * 64;
    }

    // ---- compute maps ----
    const int q_ = lane >> 4;                   // granule index 0..3
    const int lr = lane & 15;
    const int x7 = lane & 7;
    const int wm = wid >> 2;                    // 0/1 -> oc half (128 rows)
    const int wn = wid & 3;                     // 0..3 -> pos quarter (64)
    const int g0 = (q_ ^ x7) << 3;
    const int g1 = ((4 + q_) ^ x7) << 3;

    f32x4 acc[8][4] = {};

    // ---- prologue: tile0 (A+B) + tile1 B; drain to 4 outstanding ----
    STAGE_A(0, 0); STAGE_A(0, 1); STAGE_B(0, 0); STAGE_B(0, 1);
    STAGE_B(1, 0); STAGE_B(1, 1);
    asm volatile("s_waitcnt vmcnt(4)" ::: "memory");
    __builtin_amdgcn_s_barrier();

    for (int kt = 0; kt < NT; ++kt) {
        const unsigned short* Abuf = Alds[kt & 1];
        const unsigned short* Bbuf = Blds[kt & 1];
        bf16x8 bfr[4][2];
        #pragma unroll
        for (int q = 0; q < 4; ++q) {
            if (q == 0) {
                #pragma unroll
                for (int n = 0; n < 4; ++n) {
                    const unsigned short* Bb = Bbuf + (wn * 64 + n * 16 + lr) * 64;
                    bfr[n][0] = *(const bf16x8*)(Bb + g0);
                    bfr[n][1] = *(const bf16x8*)(Bb + g1);
                }
            }
            bf16x8 afr[2][2];
            #pragma unroll
            for (int mm = 0; mm < 2; ++mm) {
                const unsigned short* Ab =
                    Abuf + (wm * 128 + q * 32 + mm * 16 + lr) * 64;
                afr[mm][0] = *(const bf16x8*)(Ab + g0);
                afr[mm][1] = *(const bf16x8*)(Ab + g1);
            }
            if (q == 0)      { if (kt + 1 < NT) STAGE_A(kt + 1, 0); }
            else if (q == 1) { if (kt + 1 < NT) STAGE_A(kt + 1, 1); }
            else if (q == 2) { if (kt + 2 < NT) STAGE_B(kt + 2, 0); }
            else {
                if (kt + 2 < NT) STAGE_B(kt + 2, 1);
                if (kt + 1 < NT) {
                    if (kt + 2 < NT) asm volatile("s_waitcnt vmcnt(4)" ::: "memory");
                    else             asm volatile("s_waitcnt vmcnt(0)" ::: "memory");
                }
            }
            __builtin_amdgcn_s_barrier();
            asm volatile("s_waitcnt lgkmcnt(0)" ::: "memory");
            __builtin_amdgcn_sched_barrier(0);
            __builtin_amdgcn_s_setprio(1);
            #pragma unroll
            for (int mm = 0; mm < 2; ++mm)
                #pragma unroll
                for (int n = 0; n < 4; ++n) {
                    acc[q * 2 + mm][n] = __builtin_amdgcn_mfma_f32_16x16x32_bf16(
                        afr[mm][0], bfr[n][0], acc[q * 2 + mm][n], 0, 0, 0);
                    acc[q * 2 + mm][n] = __builtin_amdgcn_mfma_f32_16x16x32_bf16(
                        afr[mm][1], bfr[n][1], acc[q * 2 + mm][n], 0, 0, 0);
                }
            __builtin_amdgcn_s_setprio(0);
            __builtin_amdgcn_s_barrier();
        }
    }

    // ---- epilogue: BN + ReLU -> NHWC bf16 [pos][256] ----
    #pragma unroll
    for (int m = 0; m < 8; ++m) {
        const int ocm = wm * 128 + m * 16 + q_ * 4;
        float sc[4], sh[4];
        #pragma unroll
        for (int r = 0; r < 4; ++r) {
            sc[r] = P.bg[ocm + r] * rsqrtf(P.bv[ocm + r] + BN_EPS);
            sh[r] = P.bb[ocm + r] - P.bm[ocm + r] * sc[r];
        }
        #pragma unroll
        for (int n = 0; n < 4; ++n) {
            const int pg = p0 + wn * 64 + n * 16 + lr;
            if (pg < P.N) {
                unsigned e0 = f2bf(fmaxf(acc[m][n][0] * sc[0] + sh[0], 0.f));
                unsigned e1 = f2bf(fmaxf(acc[m][n][1] * sc[1] + sh[1], 0.f));
                unsigned e2 = f2bf(fmaxf(acc[m][n][2] * sc[2] + sh[2], 0.f));
                unsigned e3 = f2bf(fmaxf(acc[m][n][3] * sc[3] + sh[3], 0.f));
                uint2 v; v.x = e0 | (e1 << 16); v.y = e2 | (e3 << 16);
                *(uint2*)(P.out + (size_t)pg * 256 + ocm) = v;
            }
        }
    }
}

// ===========================================================================
// Fused xcorr + head (round-8 proven, unchanged)
// ===========================================================================
__global__ __launch_bounds__(256)
void fused_xcorr_head_kernel(const unsigned short* __restrict__ sfeat,
                             const unsigned short* __restrict__ kfeat,
                             const unsigned short* __restrict__ h1w16,
                             const unsigned short* __restrict__ h2w16,
                             const float* __restrict__ bn_g,
                             const float* __restrict__ bn_b,
                             const float* __restrict__ bn_m,
                             const float* __restrict__ bn_v,
                             const float* __restrict__ h2b,
                             float* __restrict__ out)
{
    __shared__ __align__(16) unsigned short Alds[16384];
    __shared__ __align__(16) unsigned short Xlds[64 * 264];

    const int tid  = threadIdx.x;
    const int lane = tid & 63;
    const int wid  = tid >> 6;
    const int bid  = blockIdx.x;
    const int b    = bid / 10;
    const int pt   = bid - b * 10;
    const int p0   = pt * 64;

    {
        const int c = tid;
        float kv[25];
        const unsigned short* kp = kfeat + (size_t)b * 25 * 256 + c;
        #pragma unroll
        for (int t = 0; t < 25; ++t) kv[t] = bf2f(kp[t * 256]);

        if (pt == 9) {
            #pragma unroll
            for (int j = 49; j < 64; ++j) Xlds[j * 264 + c] = 0;
        }

        const int oh0 = p0 / 25;
        for (int ohr = 0; ohr < 4; ++ohr) {
            const int oh = oh0 + ohr;
            const int jbase = oh * 25 - p0;
            if (oh <= 24 && jbase < 64) {
                float acc[25];
                #pragma unroll
                for (int z = 0; z < 25; ++z) acc[z] = 0.f;
                const unsigned short* sp =
                    sfeat + ((size_t)(b * 29 + oh)) * 29 * 256 + c;
                #pragma unroll
                for (int i = 0; i < 5; ++i)
                    #pragma unroll
                    for (int w2 = 0; w2 < 29; ++w2) {
                        const float sv = bf2f(sp[(i * 29 + w2) * 256]);
                        #pragma unroll
                        for (int t = 0; t < 5; ++t) {
                            const int ww = w2 - t;
                            if (ww >= 0 && ww <= 24)
                                acc[ww] += sv * kv[i * 5 + t];
                        }
                    }
                #pragma unroll
                for (int ow = 0; ow < 25; ++ow) {
                    const int j = jbase + ow;
                    if (j >= 0 && j < 64)
                        Xlds[j * 264 + c] = f2bf(acc[ow]);
                }
            }
        }
    }

    const int lrow = lane >> 3;
    int aoffs[8], aldsr[8];
    #pragma unroll
    for (int s = 0; s < 8; ++s) {
        const int rowb = s * 32 + wid * 8;
        const int row  = rowb + lrow;
        const int g    = (lane & 7) ^ (row & 7);
        aoffs[s] = row * 256 + g * 8;
        aldsr[s] = rowb * 64;
    }
    const int q_ = lane >> 4;
    const int lr = lane & 15;
    const int wm = wid >> 1;
    const int wn = wid & 1;
    const int g0 = q_ ^ (lane & 7);
    const int g1 = (4 + q_) ^ (lane & 7);
    const unsigned short* Abase = &Alds[(wm * 128 + lr) * 64];

    f32x4 acc1[8][2] = {};

    for (int ics = 0; ics < 4; ++ics) {
        const int ic0 = ics * 64;
        __syncthreads();
        #pragma unroll
        for (int s = 0; s < 8; ++s)
            GLDS16(h1w16 + aoffs[s] + ic0, &Alds[aldsr[s]]);
        __syncthreads();

        bf16x8 bfr[2][2];
        #pragma unroll
        for (int n = 0; n < 2; ++n) {
            const int rowp = wn * 32 + n * 16 + lr;
            bfr[n][0] = *(const bf16x8*)(Xlds + rowp * 264 + ic0 + q_ * 8);
            bfr[n][1] = *(const bf16x8*)(Xlds + rowp * 264 + ic0 + 32 + q_ * 8);
        }
        #pragma unroll
        for (int m = 0; m < 8; ++m) {
            bf16x8 a0 = *(const bf16x8*)(Abase + m * 1024 + g0 * 8);
            bf16x8 a1 = *(const bf16x8*)(Abase + m * 1024 + g1 * 8);
            #pragma unroll
            for (int n = 0; n < 2; ++n) {
                acc1[m][n] = __builtin_amdgcn_mfma_f32_16x16x32_bf16(
                                 a0, bfr[n][0], acc1[m][n], 0, 0, 0);
                acc1[m][n] = __builtin_amdgcn_mfma_f32_16x16x32_bf16(
                                 a1, bfr[n][1], acc1[m][n], 0, 0, 0);
            }
        }
    }

    __syncthreads();
    #pragma unroll
    for (int m = 0; m < 8; ++m) {
        const int ocm = wm * 128 + m * 16 + q_ * 4;
        float sc[4], sh[4];
        #pragma unroll
        for (int r = 0; r < 4; ++r) {
            sc[r] = bn_g[ocm + r] * rsqrtf(bn_v[ocm + r] + BN_EPS);
            sh[r] = bn_b[ocm + r] - bn_m[ocm + r] * sc[r];
        }
        #pragma unroll
        for (int n = 0; n < 2; ++n) {
            const int pl = wn * 32 + n * 16 + lr;
            unsigned e0 = f2bf(fmaxf(acc1[m][n][0] * sc[0] + sh[0], 0.f));
            unsigned e1 = f2bf(fmaxf(acc1[m][n][1] * sc[1] + sh[1], 0.f));
            unsigned e2 = f2bf(fmaxf(acc1[m][n][2] * sc[2] + sh[2], 0.f));
            unsigned e3 = f2bf(fmaxf(acc1[m][n][3] * sc[3] + sh[3], 0.f));
            uint2 v; v.x = e0 | (e1 << 16); v.y = e2 | (e3 << 16);
            *(uint2*)(Xlds + (size_t)pl * 264 + ocm) = v;
        }
    }
    __syncthreads();

    const int pl = wid * 16 + lr;
    const unsigned short* arow = h2w16 + lr * 256 + q_ * 8;
    const unsigned short* brow = Xlds + (size_t)pl * 264 + q_ * 8;

    f32x4 acc2 = {};
    #pragma unroll
    for (int ks = 0; ks < 8; ++ks) {
        bf16x8 a  = *(const bf16x8*)(arow + ks * 32);
        bf16x8 bb = *(const bf16x8*)(brow + ks * 32);
        acc2 = __builtin_amdgcn_mfma_f32_16x16x32_bf16(a, bb, acc2, 0, 0, 0);
    }

    const int plocal = p0 + pl;
    if (plocal < 625) {
        #pragma unroll
        for (int r = 0; r < 4; ++r) {
            const int oc = q_ * 4 + r;
            if (oc < 10)
                out[((size_t)(b * 10 + oc)) * 625 + plocal] = acc2[r] + h2b[oc];
        }
    }
}

// ===========================================================================
extern "C" void kernel_launch(void* const* d_in, const int* in_sizes, int n_in,
                              void* d_out, int out_size, void* d_ws, size_t ws_size,
                              hipStream_t stream)
{
    const float* kin  = (const float*)d_in[0];
    const float* srch = (const float*)d_in[1];
    const float* ck_w = (const float*)d_in[2];
    const float* ck_g = (const float*)d_in[3];
    const float* ck_b = (const float*)d_in[4];
    const float* ck_m = (const float*)d_in[5];
    const float* ck_v = (const float*)d_in[6];
    const float* cs_w = (const float*)d_in[7];
    const float* cs_g = (const float*)d_in[8];
    const float* cs_b = (const float*)d_in[9];
    const float* cs_m = (const float*)d_in[10];
    const float* cs_v = (const float*)d_in[11];
    const float* h1_w = (const float*)d_in[12];
    const float* h_g  = (const float*)d_in[13];
    const float* h_b  = (const float*)d_in[14];
    const float* h_m  = (const float*)d_in[15];
    const float* h_v  = (const float*)d_in[16];
    const float* h2_w = (const float*)d_in[17];
    const float* h2_b = (const float*)d_in[18];

    const int B = in_sizes[0] / (256 * 7 * 7);   // 64

    // ---- workspace layout (round-8, unchanged) ----
    uint8_t* w = (uint8_t*)d_ws;
    unsigned short* s16     = (unsigned short*)(w);             // B*31*31*256 bf16
    unsigned short* sfeat16 = (unsigned short*)(w + 31490048);  // B*841*256 bf16
    unsigned short* kf16    = (unsigned short*)(w + 59047936);  // B*25*256 bf16
    unsigned short* k16     = (unsigned short*)(w + 59867136);  // B*7*7*256 bf16
    unsigned short* wTk     = (unsigned short*)(w + 61472768);
    unsigned short* wTs     = (unsigned short*)(w + 62652416);
    unsigned short* h1w16   = (unsigned short*)(w + 63832064);
    unsigned short* h2w16   = (unsigned short*)(w + 63963136);

    const int Ns = B * 841;    // 53824
    const int Nk = B * 25;     // 1600
    const int GsT = (Ns + 255) / 256;   // 211 search pos-tiles
    const int GkT = (Nk + 255) / 256;   // 7 kernel pos-tiles
    const int GS = B * 16 * 4;          // 4096
    const int GK = B * 1 * 4;           // 256

    dim3 blk(256, 1, 1);

    // 1) prep
    hipLaunchKernelGGL(prep_kernel, dim3(GS + GK + 4880), blk, 0, stream,
                       srch, kin, cs_w, ck_w, h1_w, h2_w,
                       s16, k16, wTs, wTk, h1w16, h2w16, GS, GK);

    // 2) both 3x3 convs, 8-phase 256^2 schedule
    ConvParams S{ s16, wTs, cs_g, cs_b, cs_m, cs_v, sfeat16, 31, 31, 29, 841, Ns };
    ConvParams K{ k16, wTk, ck_g, ck_b, ck_m, ck_v, kf16, 7, 7, 5, 25, Nk };
    hipLaunchKernelGGL(conv3x3_8ph_kernel, dim3(GsT + GkT), dim3(512, 1, 1),
                       0, stream, S, K, GsT);

    // 3) fused xcorr + head -> d_out
    hipLaunchKernelGGL(fused_xcorr_head_kernel, dim3(B * 10), blk, 0, stream,
                       sfeat16, kf16, h1w16, h2w16,
                       h_g, h_b, h_m, h_v, h2_b, (float*)d_out);
}

// Round 10
// 165.159 us; speedup vs baseline: 1.0722x; 1.0722x over previous
//
#include <hip/hip_runtime.h>
#include <cstddef>
#include <cstdint>

#define BN_EPS 1e-5f

typedef __attribute__((ext_vector_type(8))) __bf16 bf16x8;
typedef __attribute__((ext_vector_type(4))) float f32x4;

__device__ inline unsigned short f2bf(float f) {
    unsigned u = __builtin_bit_cast(unsigned, f);
    unsigned r = (u + 0x7fff + ((u >> 16) & 1)) >> 16;
    return (unsigned short)r;
}
__device__ inline float bf2f(unsigned short u) {
    return __builtin_bit_cast(float, (unsigned)u << 16);
}

#define GLDS16(g, l)                                                        \
    __builtin_amdgcn_global_load_lds(                                       \
        (const __attribute__((address_space(1))) void*)(g),                 \
        (__attribute__((address_space(3))) void*)(l), 16, 0, 0)

// ===========================================================================
// Prep kernel: NCHW f32 -> NHWC bf16 transpose (fat blocks: 64 hw x 256 c
// per block, 4 sequential 64x64 tiles) + weight conversions (8 elem/thread).
// Values bit-identical to rounds 8/9 prep; only block decomposition changed.
// Block ranges: [0,GS) search, [GS,GS+GK) kernel, [GS+GK, +610) weights.
// ===========================================================================
template<int HW, int NT64>
__device__ inline void transpose_body(int rb, const float* __restrict__ in,
                                      unsigned short* __restrict__ out)
{
    __shared__ unsigned short tl[64][66];
    const int tid  = threadIdx.x;
    const int lane = tid & 63, w = tid >> 6;
    const int b  = rb / NT64, ht = rb - b * NT64;
    const int hw0 = ht * 64;
    const int hw  = hw0 + lane;
    #pragma unroll
    for (int ct = 0; ct < 4; ++ct) {
        const int c0 = ct * 64;
        const float* ib = in + ((size_t)b * 256 + c0) * HW;
        #pragma unroll
        for (int r = 0; r < 16; ++r) {
            const int cl = w * 16 + r;
            const float v = (hw < HW) ? ib[(size_t)cl * HW + hw] : 0.f;
            tl[cl][lane] = f2bf(v);
        }
        __syncthreads();
        unsigned short* ob = out + ((size_t)b * HW + hw0) * 256 + c0 + lane;
        #pragma unroll
        for (int jj = 0; jj < 16; ++jj) {
            const int j = jj * 4 + w;
            if (hw0 + j < HW) ob[(size_t)j * 256] = tl[lane][j];
        }
        __syncthreads();
    }
}

__global__ __launch_bounds__(256)
void prep_kernel(const float* __restrict__ srch, const float* __restrict__ kin,
                 const float* __restrict__ cs_w, const float* __restrict__ ck_w,
                 const float* __restrict__ h1_w, const float* __restrict__ h2_w,
                 unsigned short* __restrict__ s16, unsigned short* __restrict__ k16,
                 unsigned short* __restrict__ wTs, unsigned short* __restrict__ wTk,
                 unsigned short* __restrict__ h1w16, unsigned short* __restrict__ h2w16,
                 int GS, int GK)
{
    const int bid = blockIdx.x;
    if (bid < GS) {
        transpose_body<961, 16>(bid, srch, s16);
    } else if (bid < GS + GK) {
        transpose_body<49, 1>(bid - GS, kin, k16);
    } else {
        const int base = (bid - GS - GK) * 2048 + threadIdx.x * 8;
        #pragma unroll
        for (int u = 0; u < 8; ++u) {
            const int i = base + u;
            if (i < 589824) {
                const int ic = i & 255, t = i >> 8, oc = t & 255, khkw = t >> 8;
                wTs[i] = f2bf(cs_w[(size_t)((oc << 8) + ic) * 9 + khkw]);
            } else if (i < 1179648) {
                const int j = i - 589824;
                const int ic = j & 255, t = j >> 8, oc = t & 255, khkw = t >> 8;
                wTk[j] = f2bf(ck_w[(size_t)((oc << 8) + ic) * 9 + khkw]);
            } else if (i < 1245184) {
                const int j = i - 1179648;
                h1w16[j] = f2bf(h1_w[j]);
            } else if (i < 1249280) {
                const int j = i - 1245184;
                const int oc = j >> 8, ic = j & 255;
                h2w16[j] = (oc < 10) ? f2bf(h2_w[oc * 256 + ic]) : (unsigned short)0;
            }
        }
    }
}

// ===========================================================================
// Combined 3x3 MFMA conv + BN + ReLU for BOTH branches (rounds 6-8 proven,
// 2-phase 128^2 structure). NHWC bf16 output.
// ===========================================================================
struct ConvParams {
    const unsigned short* bsrc;
    const unsigned short* wT;
    const float *bg, *bb, *bm, *bv;
    unsigned short* out;          // NHWC bf16 [pos][256]
    int IH, IW, OW, PPB, N;
};

__global__ __launch_bounds__(256)
void conv3x3_kernel(ConvParams S, ConvParams K, int Gs)
{
    __shared__ __align__(16) unsigned short Alds[128 * 64];
    __shared__ __align__(16) unsigned short Blds[128 * 64];

    const int tid  = threadIdx.x;
    const int lane = tid & 63;
    const int wid  = tid >> 6;

    const int raw = blockIdx.x;
    ConvParams P;
    int tileid;
    if (raw < Gs) {
        P = S;
        const int q8 = Gs >> 3, r8 = Gs & 7;
        const int xcd = raw & 7, seq = raw >> 3;
        tileid = (xcd < r8 ? xcd * (q8 + 1) : r8 * (q8 + 1) + (xcd - r8) * q8) + seq;
    } else {
        P = K;
        tileid = raw - Gs;
    }
    const int pt  = tileid >> 1;
    const int oct = tileid & 1;
    const int oc0 = oct << 7;
    const int p0  = pt << 7;

    int aoff[4], brow[4], bgs8[4], ldsrow[4];
    #pragma unroll
    for (int i = 0; i < 4; ++i) {
        const int r  = i * 32 + wid * 8 + (lane >> 3);
        const int gs = (lane & 7) ^ (r & 7);
        aoff[i] = (oc0 + r) * 256 + gs * 8;
        int pg = p0 + r; if (pg > P.N - 1) pg = P.N - 1;
        const int bb_ = pg / P.PPB;
        const int p   = pg - bb_ * P.PPB;
        const int oh  = p / P.OW, ow = p - oh * P.OW;
        brow[i] = (bb_ * P.IH + oh) * P.IW + ow;
        bgs8[i] = gs * 8;
        ldsrow[i] = (i * 32 + wid * 8) * 64;
    }

    const int q_  = lane >> 4;
    const int lr  = lane & 15;
    const int wm0 = (wid >> 1) * 64;
    const int wn0 = (wid & 1) * 64;
    const int g0  = q_ ^ (lane & 7);
    const int g1  = (4 + q_) ^ (lane & 7);
    const unsigned short* Abase = &Alds[(wm0 + lr) * 64];
    const unsigned short* Bbase = &Blds[(wn0 + lr) * 64];

    f32x4 acc[4][4] = {};

    int kh = 0, kw = 0;
    for (int khkw = 0; khkw < 9; ++khkw) {
        const size_t wslice = (size_t)khkw << 16;
        const int tapadd = kh * P.IW + kw;
        for (int ics = 0; ics < 4; ++ics) {
            const int ic0 = ics * 64;
            __syncthreads();
            #pragma unroll
            for (int i = 0; i < 4; ++i) {
                GLDS16(P.wT + wslice + aoff[i] + ic0, &Alds[ldsrow[i]]);
                GLDS16(P.bsrc + (size_t)(brow[i] + tapadd) * 256 + ic0 + bgs8[i],
                       &Blds[ldsrow[i]]);
            }
            __syncthreads();

            bf16x8 bfr[4][2];
            #pragma unroll
            for (int n = 0; n < 4; ++n) {
                bfr[n][0] = *(const bf16x8*)(Bbase + n * 1024 + g0 * 8);
                bfr[n][1] = *(const bf16x8*)(Bbase + n * 1024 + g1 * 8);
            }
            #pragma unroll
            for (int m = 0; m < 4; ++m) {
                bf16x8 a0 = *(const bf16x8*)(Abase + m * 1024 + g0 * 8);
                bf16x8 a1 = *(const bf16x8*)(Abase + m * 1024 + g1 * 8);
                #pragma unroll
                for (int n = 0; n < 4; ++n) {
                    acc[m][n] = __builtin_amdgcn_mfma_f32_16x16x32_bf16(
                                    a0, bfr[n][0], acc[m][n], 0, 0, 0);
                    acc[m][n] = __builtin_amdgcn_mfma_f32_16x16x32_bf16(
                                    a1, bfr[n][1], acc[m][n], 0, 0, 0);
                }
            }
        }
        if (++kw == 3) { kw = 0; ++kh; }
    }

    #pragma unroll
    for (int m = 0; m < 4; ++m) {
        const int ocm = oc0 + wm0 + m * 16 + q_ * 4;
        float sc[4], sh[4];
        #pragma unroll
        for (int r = 0; r < 4; ++r) {
            sc[r] = P.bg[ocm + r] * rsqrtf(P.bv[ocm + r] + BN_EPS);
            sh[r] = P.bb[ocm + r] - P.bm[ocm + r] * sc[r];
        }
        #pragma unroll
        for (int n = 0; n < 4; ++n) {
            const int pg = p0 + wn0 + n * 16 + lr;
            if (pg < P.N) {
                unsigned e0 = f2bf(fmaxf(acc[m][n][0] * sc[0] + sh[0], 0.f));
                unsigned e1 = f2bf(fmaxf(acc[m][n][1] * sc[1] + sh[1], 0.f));
                unsigned e2 = f2bf(fmaxf(acc[m][n][2] * sc[2] + sh[2], 0.f));
                unsigned e3 = f2bf(fmaxf(acc[m][n][3] * sc[3] + sh[3], 0.f));
                uint2 v; v.x = e0 | (e1 << 16); v.y = e2 | (e3 << 16);
                *(uint2*)(P.out + (size_t)pg * 256 + ocm) = v;
            }
        }
    }
}

// ===========================================================================
// Fused xcorr + head (round-8 proven, unchanged)
// ===========================================================================
__global__ __launch_bounds__(256)
void fused_xcorr_head_kernel(const unsigned short* __restrict__ sfeat,
                             const unsigned short* __restrict__ kfeat,
                             const unsigned short* __restrict__ h1w16,
                             const unsigned short* __restrict__ h2w16,
                             const float* __restrict__ bn_g,
                             const float* __restrict__ bn_b,
                             const float* __restrict__ bn_m,
                             const float* __restrict__ bn_v,
                             const float* __restrict__ h2b,
                             float* __restrict__ out)
{
    __shared__ __align__(16) unsigned short Alds[16384];
    __shared__ __align__(16) unsigned short Xlds[64 * 264];

    const int tid  = threadIdx.x;
    const int lane = tid & 63;
    const int wid  = tid >> 6;
    const int bid  = blockIdx.x;
    const int b    = bid / 10;
    const int pt   = bid - b * 10;
    const int p0   = pt * 64;

    {
        const int c = tid;
        float kv[25];
        const unsigned short* kp = kfeat + (size_t)b * 25 * 256 + c;
        #pragma unroll
        for (int t = 0; t < 25; ++t) kv[t] = bf2f(kp[t * 256]);

        if (pt == 9) {
            #pragma unroll
            for (int j = 49; j < 64; ++j) Xlds[j * 264 + c] = 0;
        }

        const int oh0 = p0 / 25;
        for (int ohr = 0; ohr < 4; ++ohr) {
            const int oh = oh0 + ohr;
            const int jbase = oh * 25 - p0;
            if (oh <= 24 && jbase < 64) {
                float acc[25];
                #pragma unroll
                for (int z = 0; z < 25; ++z) acc[z] = 0.f;
                const unsigned short* sp =
                    sfeat + ((size_t)(b * 29 + oh)) * 29 * 256 + c;
                #pragma unroll
                for (int i = 0; i < 5; ++i)
                    #pragma unroll
                    for (int w2 = 0; w2 < 29; ++w2) {
                        const float sv = bf2f(sp[(i * 29 + w2) * 256]);
                        #pragma unroll
                        for (int t = 0; t < 5; ++t) {
                            const int ww = w2 - t;
                            if (ww >= 0 && ww <= 24)
                                acc[ww] += sv * kv[i * 5 + t];
                        }
                    }
                #pragma unroll
                for (int ow = 0; ow < 25; ++ow) {
                    const int j = jbase + ow;
                    if (j >= 0 && j < 64)
                        Xlds[j * 264 + c] = f2bf(acc[ow]);
                }
            }
        }
    }

    const int lrow = lane >> 3;
    int aoffs[8], aldsr[8];
    #pragma unroll
    for (int s = 0; s < 8; ++s) {
        const int rowb = s * 32 + wid * 8;
        const int row  = rowb + lrow;
        const int g    = (lane & 7) ^ (row & 7);
        aoffs[s] = row * 256 + g * 8;
        aldsr[s] = rowb * 64;
    }
    const int q_ = lane >> 4;
    const int lr = lane & 15;
    const int wm = wid >> 1;
    const int wn = wid & 1;
    const int g0 = q_ ^ (lane & 7);
    const int g1 = (4 + q_) ^ (lane & 7);
    const unsigned short* Abase = &Alds[(wm * 128 + lr) * 64];

    f32x4 acc1[8][2] = {};

    for (int ics = 0; ics < 4; ++ics) {
        const int ic0 = ics * 64;
        __syncthreads();
        #pragma unroll
        for (int s = 0; s < 8; ++s)
            GLDS16(h1w16 + aoffs[s] + ic0, &Alds[aldsr[s]]);
        __syncthreads();

        bf16x8 bfr[2][2];
        #pragma unroll
        for (int n = 0; n < 2; ++n) {
            const int rowp = wn * 32 + n * 16 + lr;
            bfr[n][0] = *(const bf16x8*)(Xlds + rowp * 264 + ic0 + q_ * 8);
            bfr[n][1] = *(const bf16x8*)(Xlds + rowp * 264 + ic0 + 32 + q_ * 8);
        }
        #pragma unroll
        for (int m = 0; m < 8; ++m) {
            bf16x8 a0 = *(const bf16x8*)(Abase + m * 1024 + g0 * 8);
            bf16x8 a1 = *(const bf16x8*)(Abase + m * 1024 + g1 * 8);
            #pragma unroll
            for (int n = 0; n < 2; ++n) {
                acc1[m][n] = __builtin_amdgcn_mfma_f32_16x16x32_bf16(
                                 a0, bfr[n][0], acc1[m][n], 0, 0, 0);
                acc1[m][n] = __builtin_amdgcn_mfma_f32_16x16x32_bf16(
                                 a1, bfr[n][1], acc1[m][n], 0, 0, 0);
            }
        }
    }

    __syncthreads();
    #pragma unroll
    for (int m = 0; m < 8; ++m) {
        const int ocm = wm * 128 + m * 16 + q_ * 4;
        float sc[4], sh[4];
        #pragma unroll
        for (int r = 0; r < 4; ++r) {
            sc[r] = bn_g[ocm + r] * rsqrtf(bn_v[ocm + r] + BN_EPS);
            sh[r] = bn_b[ocm + r] - bn_m[ocm + r] * sc[r];
        }
        #pragma unroll
        for (int n = 0; n < 2; ++n) {
            const int pl = wn * 32 + n * 16 + lr;
            unsigned e0 = f2bf(fmaxf(acc1[m][n][0] * sc[0] + sh[0], 0.f));
            unsigned e1 = f2bf(fmaxf(acc1[m][n][1] * sc[1] + sh[1], 0.f));
            unsigned e2 = f2bf(fmaxf(acc1[m][n][2] * sc[2] + sh[2], 0.f));
            unsigned e3 = f2bf(fmaxf(acc1[m][n][3] * sc[3] + sh[3], 0.f));
            uint2 v; v.x = e0 | (e1 << 16); v.y = e2 | (e3 << 16);
            *(uint2*)(Xlds + (size_t)pl * 264 + ocm) = v;
        }
    }
    __syncthreads();

    const int pl = wid * 16 + lr;
    const unsigned short* arow = h2w16 + lr * 256 + q_ * 8;
    const unsigned short* brow = Xlds + (size_t)pl * 264 + q_ * 8;

    f32x4 acc2 = {};
    #pragma unroll
    for (int ks = 0; ks < 8; ++ks) {
        bf16x8 a  = *(const bf16x8*)(arow + ks * 32);
        bf16x8 bb = *(const bf16x8*)(brow + ks * 32);
        acc2 = __builtin_amdgcn_mfma_f32_16x16x32_bf16(a, bb, acc2, 0, 0, 0);
    }

    const int plocal = p0 + pl;
    if (plocal < 625) {
        #pragma unroll
        for (int r = 0; r < 4; ++r) {
            const int oc = q_ * 4 + r;
            if (oc < 10)
                out[((size_t)(b * 10 + oc)) * 625 + plocal] = acc2[r] + h2b[oc];
        }
    }
}

// ===========================================================================
extern "C" void kernel_launch(void* const* d_in, const int* in_sizes, int n_in,
                              void* d_out, int out_size, void* d_ws, size_t ws_size,
                              hipStream_t stream)
{
    const float* kin  = (const float*)d_in[0];
    const float* srch = (const float*)d_in[1];
    const float* ck_w = (const float*)d_in[2];
    const float* ck_g = (const float*)d_in[3];
    const float* ck_b = (const float*)d_in[4];
    const float* ck_m = (const float*)d_in[5];
    const float* ck_v = (const float*)d_in[6];
    const float* cs_w = (const float*)d_in[7];
    const float* cs_g = (const float*)d_in[8];
    const float* cs_b = (const float*)d_in[9];
    const float* cs_m = (const float*)d_in[10];
    const float* cs_v = (const float*)d_in[11];
    const float* h1_w = (const float*)d_in[12];
    const float* h_g  = (const float*)d_in[13];
    const float* h_b  = (const float*)d_in[14];
    const float* h_m  = (const float*)d_in[15];
    const float* h_v  = (const float*)d_in[16];
    const float* h2_w = (const float*)d_in[17];
    const float* h2_b = (const float*)d_in[18];

    const int B = in_sizes[0] / (256 * 7 * 7);   // 64

    // ---- workspace layout (round-8, unchanged) ----
    uint8_t* w = (uint8_t*)d_ws;
    unsigned short* s16     = (unsigned short*)(w);             // B*31*31*256 bf16
    unsigned short* sfeat16 = (unsigned short*)(w + 31490048);  // B*841*256 bf16
    unsigned short* kf16    = (unsigned short*)(w + 59047936);  // B*25*256 bf16
    unsigned short* k16     = (unsigned short*)(w + 59867136);  // B*7*7*256 bf16
    unsigned short* wTk     = (unsigned short*)(w + 61472768);
    unsigned short* wTs     = (unsigned short*)(w + 62652416);
    unsigned short* h1w16   = (unsigned short*)(w + 63832064);
    unsigned short* h2w16   = (unsigned short*)(w + 63963136);

    const int Ns = B * 841;    // 53824
    const int Nk = B * 25;     // 1600
    const int Gs = 2 * ((Ns + 127) / 128);   // 842
    const int Gk = 2 * ((Nk + 127) / 128);   // 26
    const int GS = B * 16;     // 1024 search-transpose blocks (64hw x 256c each)
    const int GK = B * 1;      // 64 kernel-transpose blocks
    const int GW = 610;        // weight-conversion blocks (2048 elem each)

    dim3 blk(256, 1, 1);

    // 1) prep: fat-block transposes + 8-elem/thread weight conversions
    hipLaunchKernelGGL(prep_kernel, dim3(GS + GK + GW), blk, 0, stream,
                       srch, kin, cs_w, ck_w, h1_w, h2_w,
                       s16, k16, wTs, wTk, h1w16, h2w16, GS, GK);

    // 2) both 3x3 convs (2-phase 128^2 proven structure)
    ConvParams S{ s16, wTs, cs_g, cs_b, cs_m, cs_v, sfeat16, 31, 31, 29, 841, Ns };
    ConvParams K{ k16, wTk, ck_g, ck_b, ck_m, ck_v, kf16, 7, 7, 5, 25, Nk };
    hipLaunchKernelGGL(conv3x3_kernel, dim3(Gs + Gk), blk, 0, stream, S, K, Gs);

    // 3) fused xcorr + head -> d_out
    hipLaunchKernelGGL(fused_xcorr_head_kernel, dim3(B * 10), blk, 0, stream,
                       sfeat16, kf16, h1w16, h2w16,
                       h_g, h_b, h_m, h_v, h2_b, (float*)d_out);
}